// Round 1
// baseline (32.010 us; speedup 1.0000x reference)
//
#include <hip/hip_runtime.h>

#define HH 128
#define WW 128
#define NOUT 4096
#define TN 32   // n-columns per block
#define CH 32   // h-chunk rows staged in LDS

// corr[b,n] = (1/(H*W)) * sum_w Ew[w,n] * ( sum_h Eh[h,n] * A[b,h,w] )
// Eh[h,n] = exp(-(h/H - mu[n].x)^2 / (2 sx^2)),  Ew[w,n] = exp(-(w/W - mu[n].y)^2 / (2 sy^2))
__global__ __launch_bounds__(256) void gauss_corr_kernel(
    const float* __restrict__ act,    // [8][128][128]
    const float* __restrict__ mu,     // [4096][2]
    const float* __restrict__ sigma,  // [4096][2]
    float* __restrict__ out)          // [8][4096]
{
    __shared__ float  A_s[CH][WW];    // 16 KB, natural [h][w] layout
    __shared__ float  Eh_s[HH][TN];   // 16 KB
    __shared__ float  Ew_s[WW][TN];   // 16 KB
    __shared__ float4 musig[TN];      // mux, muy, 1/(2sx^2), 1/(2sy^2)
    __shared__ float  red[32][TN];    // 4 KB cross-thread reduction

    const int t  = threadIdx.x;
    const int n0 = blockIdx.x * TN;
    const int b  = blockIdx.y;

    const float* Ab = act + b * (HH * WW);

    // ---- issue chunk-0 A loads early (4 x float4 per thread) ----
    float4 pre[4];
    #pragma unroll
    for (int r = 0; r < 4; ++r) {
        int idx = r * 256 + t;                       // float4 index within 32x128 chunk
        pre[r] = reinterpret_cast<const float4*>(Ab)[idx];
    }

    // ---- per-n parameters ----
    if (t < TN) {
        float2 m = reinterpret_cast<const float2*>(mu)[n0 + t];
        float2 s = reinterpret_cast<const float2*>(sigma)[n0 + t];
        musig[t] = make_float4(m.x, m.y, 0.5f / (s.x * s.x), 0.5f / (s.y * s.y));
    }
    __syncthreads();

    // ---- separable Gaussian factors: 32 exps per thread ----
    #pragma unroll
    for (int r = 0; r < 16; ++r) {
        int idx = r * 256 + t;      // 0..4095
        int row = idx >> 5;         // h or w index, 0..127
        int j   = idx & 31;         // n offset within tile
        float4 ms = musig[j];
        float g  = (float)row * (1.0f / 128.0f);
        float dh = g - ms.x;
        float dw = g - ms.y;
        Eh_s[row][j] = __expf(-dh * dh * ms.z);
        Ew_s[row][j] = __expf(-dw * dw * ms.w);
    }

    const int ti = t >> 3;   // 0..31 : w-group (4 w each) -> covers 128 w
    const int tj = t & 7;    // 0..7  : n-group (4 n each) -> covers 32 n

    float acc[4][4] = {{0.f,0.f,0.f,0.f},{0.f,0.f,0.f,0.f},
                       {0.f,0.f,0.f,0.f},{0.f,0.f,0.f,0.f}};

    // ---- K-loop over h in 4 staged chunks: U[w,n] += Eh[h,n]*A[h,w] ----
    for (int c = 0; c < 4; ++c) {
        __syncthreads();   // previous chunk's reads of A_s complete
        #pragma unroll
        for (int r = 0; r < 4; ++r) {
            int idx = r * 256 + t;
            reinterpret_cast<float4*>(&A_s[0][0])[idx] = pre[r];
        }
        if (c < 3) {       // issue next chunk's loads; in flight during compute
            const float4* src = reinterpret_cast<const float4*>(Ab + (c + 1) * CH * WW);
            #pragma unroll
            for (int r = 0; r < 4; ++r) {
                int idx = r * 256 + t;
                pre[r] = src[idx];
            }
        }
        __syncthreads();   // staged chunk visible

        const int h0 = c * CH;
        #pragma unroll 4
        for (int h = 0; h < CH; ++h) {
            float4 aM = *reinterpret_cast<const float4*>(&A_s[h][ti * 4]);
            float4 eN = *reinterpret_cast<const float4*>(&Eh_s[h0 + h][tj * 4]);
            float am[4] = {aM.x, aM.y, aM.z, aM.w};
            float en[4] = {eN.x, eN.y, eN.z, eN.w};
            #pragma unroll
            for (int i = 0; i < 4; ++i)
                #pragma unroll
                for (int j = 0; j < 4; ++j)
                    acc[i][j] += am[i] * en[j];
        }
    }

    // ---- epilogue: fold Ew, reduce over the 32 w-groups ----
    float val[4];
    #pragma unroll
    for (int j = 0; j < 4; ++j) {
        float s = 0.f;
        #pragma unroll
        for (int i = 0; i < 4; ++i)
            s += Ew_s[ti * 4 + i][tj * 4 + j] * acc[i][j];
        val[j] = s;
    }
    __syncthreads();            // K-loop fully done everywhere
    #pragma unroll
    for (int j = 0; j < 4; ++j)
        red[ti][tj * 4 + j] = val[j];
    __syncthreads();

    if (t < TN) {
        float s = 0.f;
        #pragma unroll
        for (int g = 0; g < 32; ++g)
            s += red[g][t];
        out[b * NOUT + n0 + t] = s * (1.0f / 16384.0f);
    }
}

extern "C" void kernel_launch(void* const* d_in, const int* in_sizes, int n_in,
                              void* d_out, int out_size, void* d_ws, size_t ws_size,
                              hipStream_t stream) {
    const float* act   = (const float*)d_in[0];   // 8*128*128
    const float* mu    = (const float*)d_in[1];   // 4096*2
    const float* sigma = (const float*)d_in[2];   // 4096*2
    float* out = (float*)d_out;                   // 8*4096

    dim3 grid(NOUT / TN, 8);   // (128, 8)
    gauss_corr_kernel<<<grid, 256, 0, stream>>>(act, mu, sigma, out);
}

// Round 2
// 16.165 us; speedup vs baseline: 1.9803x; 1.9803x over previous
//
#include <hip/hip_runtime.h>

#define NOUT 4096
#define TN 32

typedef short bf16x8 __attribute__((ext_vector_type(8)));
typedef float f32x4  __attribute__((ext_vector_type(4)));

__device__ __forceinline__ unsigned short f2bf(float x) {
    unsigned u = __float_as_uint(x);
    u = (u + 0x7fffu + ((u >> 16) & 1u)) >> 16;   // RNE
    return (unsigned short)u;
}
__device__ __forceinline__ float bf2f(unsigned short h) {
    return __uint_as_float(((unsigned)h) << 16);
}

// corr[b,n] = (1/16384) * sum_h Eh[h,n] * sum_w Ew[w,n] * A[b,h,w]
// MFMA 16x16x32 bf16:  M=n (Ew as A-operand, hi/lo split),
//                      N=h (activation as B-operand, hi/lo split, straight from global),
//                      K=w.  Eh folded in fp32 at the epilogue.
__global__ __launch_bounds__(256) void gauss_mfma_kernel(
    const float* __restrict__ act,    // [8][128][128]
    const float* __restrict__ mu,     // [4096][2]
    const float* __restrict__ sigma,  // [4096][2]
    float* __restrict__ out)          // [8][4096]
{
    __shared__ unsigned short EwH[32][136];   // bf16 hi, +8 pad per row
    __shared__ unsigned short EwL[32][136];   // bf16 lo
    __shared__ float4 musig[32];              // mux, muy, 1/(2sx^2), 1/(2sy^2)
    __shared__ float  red[4][32];

    const int t    = threadIdx.x;
    const int wv   = t >> 6;          // wave 0..3 -> h-range [wv*32, wv*32+32)
    const int lane = t & 63;
    const int lm   = lane & 15;       // B n-col / A m-row lane index
    const int lg   = lane >> 4;       // k-group 0..3
    const int n0   = blockIdx.x * TN;
    const int b    = blockIdx.y;
    const float* Ab = act + b * 16384;

    // ---- issue A loads for ks=0,1 immediately (hide under exp phase) ----
    const float* rowA[2];
    rowA[0] = Ab + (wv * 32 + lm) * 128;        // nh = 0
    rowA[1] = Ab + (wv * 32 + 16 + lm) * 128;   // nh = 1
    float4 pre[2][2][2];   // [slot][nh][half]; indices all compile-time (unrolled)
    #pragma unroll
    for (int ks = 0; ks < 2; ++ks)
        #pragma unroll
        for (int nh = 0; nh < 2; ++nh) {
            const float4* p = reinterpret_cast<const float4*>(rowA[nh] + ks * 32 + lg * 8);
            pre[ks][nh][0] = p[0];
            pre[ks][nh][1] = p[1];
        }

    // ---- per-n params ----
    if (t < TN) {
        float2 m = reinterpret_cast<const float2*>(mu)[n0 + t];
        float2 s = reinterpret_cast<const float2*>(sigma)[n0 + t];
        musig[t] = make_float4(m.x, m.y, 0.5f / (s.x * s.x), 0.5f / (s.y * s.y));
    }
    __syncthreads();

    // ---- Ew -> LDS as bf16 hi/lo (each value computed once; 16 exps/thread) ----
    #pragma unroll
    for (int r = 0; r < 8; ++r) {
        int p  = r * 256 + t;         // 0..2047 w-pairs
        int n  = p >> 6;              // 0..31 (wave-uniform)
        int wp = p & 63;              // pair index -> w = 2wp, 2wp+1
        float4 ms = musig[n];
        float g0 = (float)(2 * wp)     * (1.0f / 128.0f);
        float g1 = (float)(2 * wp + 1) * (1.0f / 128.0f);
        float d0 = g0 - ms.y, d1 = g1 - ms.y;
        float e0 = __expf(-d0 * d0 * ms.w);
        float e1 = __expf(-d1 * d1 * ms.w);
        unsigned short h0 = f2bf(e0), h1 = f2bf(e1);
        unsigned short l0 = f2bf(e0 - bf2f(h0)), l1 = f2bf(e1 - bf2f(h1));
        *reinterpret_cast<unsigned*>(&EwH[n][2 * wp]) = (unsigned)h0 | ((unsigned)h1 << 16);
        *reinterpret_cast<unsigned*>(&EwL[n][2 * wp]) = (unsigned)l0 | ((unsigned)l1 << 16);
    }
    __syncthreads();

    // ---- MFMA K-loop over w (4 k-steps of 32) ----
    f32x4 acc[2][2] = {};   // [mf (n half)][nh (h half)]
    #pragma unroll
    for (int ks = 0; ks < 4; ++ks) {
        const int cur = ks & 1;

        // convert staged A rows to bf16 hi/lo fragments
        bf16x8 ahi[2], alo[2];
        #pragma unroll
        for (int nh = 0; nh < 2; ++nh) {
            float a[8] = { pre[cur][nh][0].x, pre[cur][nh][0].y, pre[cur][nh][0].z, pre[cur][nh][0].w,
                           pre[cur][nh][1].x, pre[cur][nh][1].y, pre[cur][nh][1].z, pre[cur][nh][1].w };
            #pragma unroll
            for (int j = 0; j < 8; ++j) {
                unsigned short hb = f2bf(a[j]);
                ahi[nh][j] = (short)hb;
                alo[nh][j] = (short)f2bf(a[j] - bf2f(hb));
            }
        }
        // prefetch ks+2
        if (ks < 2) {
            #pragma unroll
            for (int nh = 0; nh < 2; ++nh) {
                const float4* p = reinterpret_cast<const float4*>(rowA[nh] + (ks + 2) * 32 + lg * 8);
                pre[cur][nh][0] = p[0];
                pre[cur][nh][1] = p[1];
            }
        }
        // Ew fragments from LDS (broadcast across waves)
        bf16x8 ewh[2], ewl[2];
        #pragma unroll
        for (int mf = 0; mf < 2; ++mf) {
            ewh[mf] = *reinterpret_cast<const bf16x8*>(&EwH[mf * 16 + lm][ks * 32 + lg * 8]);
            ewl[mf] = *reinterpret_cast<const bf16x8*>(&EwL[mf * 16 + lm][ks * 32 + lg * 8]);
        }
        // 12 MFMAs: (hi,hi) (hi,lo) (lo,hi)
        #pragma unroll
        for (int mf = 0; mf < 2; ++mf)
            #pragma unroll
            for (int nh = 0; nh < 2; ++nh) {
                acc[mf][nh] = __builtin_amdgcn_mfma_f32_16x16x32_bf16(ewh[mf], ahi[nh], acc[mf][nh], 0, 0, 0);
                acc[mf][nh] = __builtin_amdgcn_mfma_f32_16x16x32_bf16(ewh[mf], alo[nh], acc[mf][nh], 0, 0, 0);
                acc[mf][nh] = __builtin_amdgcn_mfma_f32_16x16x32_bf16(ewl[mf], ahi[nh], acc[mf][nh], 0, 0, 0);
            }
    }

    // ---- epilogue: fold Eh (fp32, in-register), reduce over h ----
    // D layout: col(h within 16) = lane&15, row(n within 16) = 4*lg + r
    const float gh0 = (float)(wv * 32 + lm)      * (1.0f / 128.0f);
    const float gh1 = (float)(wv * 32 + 16 + lm) * (1.0f / 128.0f);
    float s8[2][4];
    #pragma unroll
    for (int mf = 0; mf < 2; ++mf)
        #pragma unroll
        for (int r = 0; r < 4; ++r) {
            int n = mf * 16 + 4 * lg + r;
            float4 ms = musig[n];
            float d0 = gh0 - ms.x, d1 = gh1 - ms.x;
            float e0 = __expf(-d0 * d0 * ms.z);
            float e1 = __expf(-d1 * d1 * ms.z);
            float v = e0 * acc[mf][0][r] + e1 * acc[mf][1][r];
            v += __shfl_xor(v, 1, 64);
            v += __shfl_xor(v, 2, 64);
            v += __shfl_xor(v, 4, 64);
            v += __shfl_xor(v, 8, 64);
            s8[mf][r] = v;            // full 16-h sum on lanes with lm==0
        }
    if (lm == 0) {
        #pragma unroll
        for (int mf = 0; mf < 2; ++mf)
            #pragma unroll
            for (int r = 0; r < 4; ++r)
                red[wv][mf * 16 + 4 * lg + r] = s8[mf][r];
    }
    __syncthreads();

    if (t < TN) {
        float s = red[0][t] + red[1][t] + red[2][t] + red[3][t];
        out[b * NOUT + n0 + t] = s * (1.0f / 16384.0f);
    }
}

extern "C" void kernel_launch(void* const* d_in, const int* in_sizes, int n_in,
                              void* d_out, int out_size, void* d_ws, size_t ws_size,
                              hipStream_t stream) {
    const float* act   = (const float*)d_in[0];
    const float* mu    = (const float*)d_in[1];
    const float* sigma = (const float*)d_in[2];
    float* out = (float*)d_out;

    dim3 grid(NOUT / TN, 8);   // (128, 8)
    gauss_mfma_kernel<<<grid, 256, 0, stream>>>(act, mu, sigma, out);
}